// Round 1
// 2264.362 us; speedup vs baseline: 1.4413x; 1.4413x over previous
//
#include <hip/hip_runtime.h>
#include <cstdint>
#include <cstddef>

// Problem constants
#define TT 1024
#define NB 64
#define HD 256
#define NG 768   // 3*H

typedef short bhalf8 __attribute__((ext_vector_type(8)));   // 8 bf16 (4 VGPRs)
typedef float f32x4  __attribute__((ext_vector_type(4)));   // MFMA accumulator

__device__ __forceinline__ unsigned short f2bf(float f) {
  unsigned u = __float_as_uint(f);
  unsigned r = (u + 0x7FFFu + ((u >> 16) & 1u)) >> 16;   // RNE
  return (unsigned short)r;
}
__device__ __forceinline__ float bf2f(unsigned short s) {
  return __uint_as_float(((unsigned)s) << 16);
}
// rcp-based activations: v_exp + v_rcp only (no IEEE div expansion).
// rcp(inf)=0, exp underflow->0 => correct saturation at +-inf.
__device__ __forceinline__ float sigm(float x) {
  return __builtin_amdgcn_rcpf(1.0f + __expf(-x));
}
__device__ __forceinline__ float tanh_fast(float x) {
  return 1.0f - 2.0f * __builtin_amdgcn_rcpf(__expf(2.0f * x) + 1.0f);
}

// gx layout: [dir][slice(4)][t][g][b16]  (slice = batch/16, b16 = batch%16)
// -> each rec block reads a private contiguous 50 MB stream (no partial-line
//    sharing across XCDs), and gx stores/loads are 8B-aligned ushort4.
#define GX_SLICE ((size_t)TT * NG * 16)

// ---------------------------------------------------------------------------
// Kernel 1: gx = X @ W_ih^T + biases, bf16, swizzled layout. Each block owns
// a 64-gate tile and 4 consecutive timesteps (W tile staged once per dir,
// reused across the 4 X tiles).
// ---------------------------------------------------------------------------
__launch_bounds__(256, 2)
__global__ void gx_kernel(const float* __restrict__ X,
                          const float* __restrict__ wih_f, const float* __restrict__ bih_f,
                          const float* __restrict__ bhh_f,
                          const float* __restrict__ wih_b, const float* __restrict__ bih_b,
                          const float* __restrict__ bhh_b,
                          unsigned short* __restrict__ gx) {
  const int tid = threadIdx.x;
  const int n0  = blockIdx.x * 64;     // gate-col tile
  const int t0  = blockIdx.y * 4;

  __shared__ unsigned short Al[64][264];   // X tile   [b][k]
  __shared__ unsigned short Bl[64][264];   // wih tile [g][k]

  const int lane = tid & 63, w = tid >> 6, quad = lane >> 4, l15 = lane & 15;

  for (int dir = 0; dir < 2; ++dir) {
    const float* wih = dir ? wih_b : wih_f;
    const float* bih = dir ? bih_b : bih_f;
    const float* bhh = dir ? bhh_b : bhh_f;
    unsigned short* gxd = gx + (size_t)dir * 4 * GX_SLICE;

    __syncthreads();   // previous readers of Bl done
#pragma unroll
    for (int i = 0; i < 16; ++i) {
      int f4  = tid + i * 256;
      int row = f4 >> 6;
      int kk  = (f4 & 63) * 4;
      float4 wv = *(const float4*)(wih + (size_t)(n0 + row) * HD + kk);
      Bl[row][kk + 0] = f2bf(wv.x); Bl[row][kk + 1] = f2bf(wv.y);
      Bl[row][kk + 2] = f2bf(wv.z); Bl[row][kk + 3] = f2bf(wv.w);
    }

    for (int tt = 0; tt < 4; ++tt) {
      const int t = t0 + tt;
      __syncthreads();   // previous readers of Al done (also publishes Bl)
#pragma unroll
      for (int i = 0; i < 16; ++i) {
        int f4  = tid + i * 256;
        int row = f4 >> 6;
        int kk  = (f4 & 63) * 4;
        float4 xv = *(const float4*)(X + ((size_t)row * TT + t) * HD + kk);
        Al[row][kk + 0] = f2bf(xv.x); Al[row][kk + 1] = f2bf(xv.y);
        Al[row][kk + 2] = f2bf(xv.z); Al[row][kk + 3] = f2bf(xv.w);
      }
      __syncthreads();

      f32x4 acc[4];
#pragma unroll
      for (int jt = 0; jt < 4; ++jt) { acc[jt][0]=0.f; acc[jt][1]=0.f; acc[jt][2]=0.f; acc[jt][3]=0.f; }

#pragma unroll
      for (int kt = 0; kt < 8; ++kt) {
        bhalf8 a = *(const bhalf8*)&Al[16 * w + l15][kt * 32 + quad * 8];
#pragma unroll
        for (int jt = 0; jt < 4; ++jt) {
          bhalf8 b = *(const bhalf8*)&Bl[jt * 16 + l15][kt * 32 + quad * 8];
          acc[jt] = __builtin_amdgcn_mfma_f32_16x16x32_bf16(a, b, acc[jt], 0, 0, 0);
        }
      }

      // store: slice = w (batch rows 16w..16w+15), b16 = quad*4+r
      unsigned short* gs = gxd + w * GX_SLICE + (size_t)t * NG * 16;
#pragma unroll
      for (int jt = 0; jt < 4; ++jt) {
        int g = n0 + jt * 16 + l15;
        float bias = bih[g] + bhh[g];
        ushort4 pk;
        pk.x = f2bf(acc[jt][0] + bias); pk.y = f2bf(acc[jt][1] + bias);
        pk.z = f2bf(acc[jt][2] + bias); pk.w = f2bf(acc[jt][3] + bias);
        *(ushort4*)(gs + g * 16 + quad * 4) = pk;
      }
    }
  }
}

// ---------------------------------------------------------------------------
// Kernel 2: recurrence. 8 blocks = 2 dirs x 4 batch-slices of 16.
// 512 threads = 8 waves. amdgpu_waves_per_eu(2,2) pins a 256-reg/wave budget
// (launch_bounds(512,1) did NOT: backend capped at 128 -> W spilled to
// scratch, reloaded every step = rounds 1-3 killer). Per wave: 6 gate-tiles;
// W frags for 5 tiles in VGPRs (160 regs) + 1 tile in LDS. h exchanged via
// double-buffered fragment-layout LDS hk[kt][lane] (lane-linear b128 reads);
// c in fp32 regs; gx prefetched one step ahead as D-layout ushort4 walked by
// a uniform (SGPR) pointer: no per-step 64-bit multiply or clamp.
// ---------------------------------------------------------------------------
__attribute__((amdgpu_flat_work_group_size(512, 512)))
__attribute__((amdgpu_waves_per_eu(2, 2)))
__global__ void rec_kernel(const float* __restrict__ whh_f,
                           const float* __restrict__ whh_b,
                           const unsigned short* __restrict__ gx,
                           float* __restrict__ out) {
  const int tid  = threadIdx.x;
  const int lane = tid & 63, w = tid >> 6, quad = lane >> 4, l15 = lane & 15;
  const int blk = blockIdx.x;          // 0..7
  const int dir = blk >> 2;
  const int b0  = (blk & 3) * 16;
  const float* whh = dir ? whh_b : whh_f;
  const unsigned short* gxd = gx + (size_t)dir * 4 * GX_SLICE + (size_t)(blk & 3) * GX_SLICE;
  float* hn = out + (size_t)TT * NB * 512;
  float* cn = hn + (size_t)NB * 512;

  __shared__ uint4 wlds[8][8][64];   // 64 KB: [wave][kt][lane] W-frags, tile p=5
  __shared__ uint4 hk[2][8][64];     // 16 KB: [buf][kt][chunk] h fragment layout
  // chunk = quad*16 + m : holds A[m][kt*32+quad*8 .. +8) as 8 bf16

  // ---- load W_hh fragments (one-time). p = g3*2 + jn ----
  bhalf8 wreg[5][8];
#pragma unroll
  for (int p = 0; p < 6; ++p) {
    int n = (p >> 1) * 256 + 32 * w + (p & 1) * 16 + l15;   // gate row
#pragma unroll
    for (int kt = 0; kt < 8; ++kt) {
      const float* wp = whh + (size_t)n * HD + kt * 32 + quad * 8;
      float4 v0 = *(const float4*)wp;
      float4 v1 = *(const float4*)(wp + 4);
      union { unsigned short us[8]; bhalf8 v; uint4 u; } pk;
      pk.us[0] = f2bf(v0.x); pk.us[1] = f2bf(v0.y); pk.us[2] = f2bf(v0.z); pk.us[3] = f2bf(v0.w);
      pk.us[4] = f2bf(v1.x); pk.us[5] = f2bf(v1.y); pk.us[6] = f2bf(v1.z); pk.us[7] = f2bf(v1.w);
      if (p < 5) wreg[p][kt] = pk.v;
      else       wlds[w][kt][lane] = pk.u;
    }
  }

  // zero h_0 buffer (only hk[0] read at s=0)
  {
    uint4 z; z.x = z.y = z.z = z.w = 0;
    for (int i = tid; i < 8 * 64; i += 512) ((uint4*)hk[0])[i] = z;
  }

  float cstate[2][4];
#pragma unroll
  for (int jn = 0; jn < 2; ++jn)
#pragma unroll
    for (int r = 0; r < 4; ++r) cstate[jn][r] = 0.0f;

  int goff[6];
#pragma unroll
  for (int p = 0; p < 6; ++p) {
    int g = (p >> 1) * 256 + 32 * w + (p & 1) * 16 + l15;
    goff[p] = g * 16 + quad * 4;     // within-slice offset (b16 = quad*4..+3)
  }

  __syncthreads();

  // uniform gx walk pointer (SGPR side): t=0 forward, t=TT-1 backward.
  // Final (unused) prefetch one step past the range stays inside the 192 MiB
  // workspace for both directions (dir0 slice3 walks into dir1 slice0's
  // region; dir1 slice0 walks back into dir0 slice3's region).
  const unsigned short* gptr = gxd + (size_t)(dir ? (TT - 1) : 0) * NG * 16;
  const ptrdiff_t gstep = dir ? -(ptrdiff_t)((size_t)NG * 16) : (ptrdiff_t)((size_t)NG * 16);

  // initial gx prefetch (s = 0)
  ushort4 gxv[6];
#pragma unroll
  for (int p = 0; p < 6; ++p) gxv[p] = *(const ushort4*)(gptr + goff[p]);

#pragma unroll 2
  for (int s = 0; s < TT; ++s) {
    const int tr = dir ? (TT - 1 - s) : s;
    const int pb = s & 1;

    // accumulator init straight from gx (D layout matches ushort4 lanes)
    f32x4 acc[6];
#pragma unroll
    for (int p = 0; p < 6; ++p) {
      acc[p][0] = bf2f(gxv[p].x); acc[p][1] = bf2f(gxv[p].y);
      acc[p][2] = bf2f(gxv[p].z); acc[p][3] = bf2f(gxv[p].w);
    }
    // prefetch next step's gx (one-past-range on last step; values unused)
    gptr += gstep;
#pragma unroll
    for (int p = 0; p < 6; ++p) gxv[p] = *(const ushort4*)(gptr + goff[p]);

    // gates += h @ W_hh^T ; A-frag read is lane-linear (conflict-free)
#pragma unroll
    for (int kt = 0; kt < 8; ++kt) {
      bhalf8 a = __builtin_bit_cast(bhalf8, hk[pb][kt][lane]);
#pragma unroll
      for (int p = 0; p < 5; ++p)
        acc[p] = __builtin_amdgcn_mfma_f32_16x16x32_bf16(a, wreg[p][kt], acc[p], 0, 0, 0);
      acc[5] = __builtin_amdgcn_mfma_f32_16x16x32_bf16(
          a, __builtin_bit_cast(bhalf8, wlds[w][kt][lane]), acc[5], 0, 0, 0);
    }

    // epilogue: coupled-gate update
    float* orow = out + ((size_t)tr * NB + b0 + quad * 4) * 512 + dir * 256 + 32 * w + l15;
    unsigned short* hnext = (unsigned short*)hk[pb ^ 1][w];   // this wave's kt-block == w
#pragma unroll
    for (int jn = 0; jn < 2; ++jn) {
#pragma unroll
      for (int r = 0; r < 4; ++r) {
        float ig = sigm(acc[jn][r]);
        float cg = tanh_fast(acc[2 + jn][r]);
        float og = sigm(acc[4 + jn][r]);
        float cp = cstate[jn][r];
        float cv = __builtin_fmaf(ig, cg - cp, cp);   // (1-ig)*cp + ig*cg
        cstate[jn][r] = cv;
        float hv = og * tanh_fast(cv);
        orow[(size_t)r * 512 + jn * 16] = hv;
        // h -> fragment layout: col = 32w + jn*16 + l15  (kt block = w),
        // chunk = quad'*16 + brow', quad' = jn*2 + (l15>>3)
        int chunk = (jn * 2 + (l15 >> 3)) * 16 + quad * 4 + r;
        hnext[chunk * 8 + (l15 & 7)] = f2bf(hv);
        if (s == TT - 1) {
          int brow = b0 + quad * 4 + r;
          int col  = 32 * w + jn * 16 + l15;
          hn[(size_t)brow * 512 + dir * 256 + col] = hv;
          cn[(size_t)brow * 512 + dir * 256 + col] = cv;
        }
      }
    }
    __syncthreads();   // h_{s+1} published before next step's A reads
  }
}

// ---------------------------------------------------------------------------
extern "C" void kernel_launch(void* const* d_in, const int* in_sizes, int n_in,
                              void* d_out, int out_size, void* d_ws, size_t ws_size,
                              hipStream_t stream) {
  const float* X     = (const float*)d_in[0];
  const float* wih_f = (const float*)d_in[1];
  const float* whh_f = (const float*)d_in[2];
  const float* bih_f = (const float*)d_in[3];
  const float* bhh_f = (const float*)d_in[4];
  const float* wih_b = (const float*)d_in[5];
  const float* whh_b = (const float*)d_in[6];
  const float* bih_b = (const float*)d_in[7];
  const float* bhh_b = (const float*)d_in[8];
  float* out = (float*)d_out;
  unsigned short* gxbuf = (unsigned short*)d_ws;   // 2*1024*768*64*2B = 192 MiB

  dim3 g1(NG / 64, TT / 4);
  gx_kernel<<<g1, 256, 0, stream>>>(X, wih_f, bih_f, bhh_f, wih_b, bih_b, bhh_b, gxbuf);
  rec_kernel<<<8, 512, 0, stream>>>(whh_f, whh_b, gxbuf, out);
}